// Round 1
// baseline (3648.932 us; speedup 1.0000x reference)
//
#include <hip/hip_runtime.h>

typedef unsigned short ushort8v __attribute__((ext_vector_type(8)));
typedef unsigned short ushort4v __attribute__((ext_vector_type(4)));

#define SS_SHIFT 64
#define LMASK 16383
#define SQRT_C 22.627416997969522f
#define LOGIT_MAXV 4.605170185988091f

__device__ __forceinline__ float bf2f(unsigned short u) {
  unsigned int x = ((unsigned int)u) << 16;
  return __builtin_bit_cast(float, x);
}
__device__ __forceinline__ unsigned short f2bf(float f) {
  unsigned int x = __builtin_bit_cast(unsigned int, f);
  x = x + 0x7FFFu + ((x >> 16) & 1u);
  return (unsigned short)(x >> 16);
}

// C[M,N] = A[M,K] * B[N,K]^T + bias ; optional SiLU epilogue; optional roll of A rows.
// 128x128 tile, BK=16, 256 threads, 8x8 per thread, fp32 accumulate.
template<int TA_BF16, int TO_BF16, int EPI, int ROLLA>
__global__ __launch_bounds__(256) void gemm_k(const void* __restrict__ Ap,
    const float* __restrict__ Bw, const float* __restrict__ bias,
    void* __restrict__ Cp, int M, int N, int K) {
  __shared__ float As[16][132];
  __shared__ float Bs[16][132];
  const int tid = threadIdx.x;
  const int tx = tid & 15, ty = tid >> 4;
  const int m0 = blockIdx.x * 128, n0 = blockIdx.y * 128;
  float acc[8][8] = {};

  for (int k0 = 0; k0 < K; k0 += 16) {
    if constexpr (TA_BF16 != 0) {
      const unsigned short* A = (const unsigned short*)Ap;
      const int row = tid >> 1, h8 = (tid & 1) * 8;
      const long gr = m0 + row;
      ushort8v u = *(const ushort8v*)(A + gr * (long)K + k0 + h8);
      #pragma unroll
      for (int e = 0; e < 8; ++e) As[h8 + e][row] = bf2f(u[e]);
    } else {
      const float* A = (const float*)Ap;
      #pragma unroll
      for (int cc = 0; cc < 2; ++cc) {
        const int c = tid + cc * 256;
        const int row = c >> 2, q4 = (c & 3) * 4;
        long gr = m0 + row;
        if constexpr (ROLLA != 0) {
          long b = gr >> 14, l = gr & LMASK;
          gr = (b << 14) + ((l + SS_SHIFT) & LMASK);
        }
        float4 v = *(const float4*)(A + gr * (long)K + k0 + q4);
        As[q4 + 0][row] = v.x; As[q4 + 1][row] = v.y;
        As[q4 + 2][row] = v.z; As[q4 + 3][row] = v.w;
      }
    }
    #pragma unroll
    for (int cc = 0; cc < 2; ++cc) {
      const int c = tid + cc * 256;
      const int row = c >> 2, q4 = (c & 3) * 4;
      float4 v = *(const float4*)(Bw + (long)(n0 + row) * K + k0 + q4);
      Bs[q4 + 0][row] = v.x; Bs[q4 + 1][row] = v.y;
      Bs[q4 + 2][row] = v.z; Bs[q4 + 3][row] = v.w;
    }
    __syncthreads();
    #pragma unroll
    for (int kk = 0; kk < 16; ++kk) {
      float a[8], b[8];
      *(float4*)(a)     = *(const float4*)&As[kk][ty * 8];
      *(float4*)(a + 4) = *(const float4*)&As[kk][ty * 8 + 4];
      *(float4*)(b)     = *(const float4*)&Bs[kk][tx * 8];
      *(float4*)(b + 4) = *(const float4*)&Bs[kk][tx * 8 + 4];
      #pragma unroll
      for (int i = 0; i < 8; ++i)
        #pragma unroll
        for (int j = 0; j < 8; ++j)
          acc[i][j] = fmaf(a[i], b[j], acc[i][j]);
    }
    __syncthreads();
  }

  float bv[8];
  #pragma unroll
  for (int j = 0; j < 8; ++j) bv[j] = bias[n0 + tx * 8 + j];
  #pragma unroll
  for (int i = 0; i < 8; ++i) {
    const long row = m0 + ty * 8 + i;
    float o[8];
    #pragma unroll
    for (int j = 0; j < 8; ++j) {
      float v = acc[i][j] + bv[j];
      if constexpr (EPI == 1) v = v / (1.f + __expf(-v));  // SiLU
      o[j] = v;
    }
    const long base = row * (long)N + n0 + tx * 8;
    if constexpr (TO_BF16 != 0) {
      ushort8v s;
      #pragma unroll
      for (int j = 0; j < 8; ++j) s[j] = f2bf(o[j]);
      *(ushort8v*)((unsigned short*)Cp + base) = s;
    } else {
      float* C = (float*)Cp;
      *(float4*)(C + base)     = make_float4(o[0], o[1], o[2], o[3]);
      *(float4*)(C + base + 4) = make_float4(o[4], o[5], o[6], o[7]);
    }
  }
}

// One block per (head, window). q/k/v staged in LDS, cosine attention + CPB bias
// + shift mask + softmax in registers (2 threads per query row).
__global__ __launch_bounds__(256) void attn_k(const unsigned short* __restrict__ qkv,
    const float* __restrict__ logit_scale, const float* __restrict__ sig_tbl,
    unsigned short* __restrict__ attnout) {
  __shared__ float qs[128][36];
  __shared__ float ks[128][36];
  __shared__ float vs[128][36];
  __shared__ float qinv[128], kinv[128], lbias[256];
  const int h = blockIdx.x;
  const int w = blockIdx.y;
  const int tid = threadIdx.x;

  #pragma unroll
  for (int cc = 0; cc < 2; ++cc) {
    const int c = tid + cc * 256;
    const int row = c >> 2, p8 = (c & 3) * 8;
    const long rbase = (long)(w * 128 + row) * 1536 + h * 32 + p8;
    ushort8v uq = *(const ushort8v*)(qkv + rbase);
    ushort8v uk = *(const ushort8v*)(qkv + rbase + 512);
    ushort8v uv = *(const ushort8v*)(qkv + rbase + 1024);
    #pragma unroll
    for (int e = 0; e < 8; ++e) {
      qs[row][p8 + e] = bf2f(uq[e]);
      ks[row][p8 + e] = bf2f(uk[e]);
      vs[row][p8 + e] = bf2f(uv[e]);
    }
  }
  if (tid < 255) lbias[tid] = sig_tbl[tid * 16 + h];
  __syncthreads();

  const float scale = __expf(fminf(logit_scale[h], LOGIT_MAXV));
  {
    const int r = tid & 127;
    float s = 0.f;
    if (tid < 128) {
      #pragma unroll
      for (int d = 0; d < 32; d += 4) {
        float4 v = *(const float4*)&qs[r][d];
        s += v.x * v.x + v.y * v.y + v.z * v.z + v.w * v.w;
      }
      qinv[r] = scale / fmaxf(sqrtf(s), 1e-12f);
    } else {
      #pragma unroll
      for (int d = 0; d < 32; d += 4) {
        float4 v = *(const float4*)&ks[r][d];
        s += v.x * v.x + v.y * v.y + v.z * v.z + v.w * v.w;
      }
      kinv[r] = 1.f / fmaxf(sqrtf(s), 1e-12f);
    }
  }
  __syncthreads();

  const int i = tid >> 1, jh = tid & 1;
  float qr[32];
  {
    const float qi = qinv[i];
    #pragma unroll
    for (int d = 0; d < 32; d += 4) {
      float4 v = *(const float4*)&qs[i][d];
      qr[d] = v.x * qi; qr[d + 1] = v.y * qi; qr[d + 2] = v.z * qi; qr[d + 3] = v.w * qi;
    }
  }
  // shift mask: only last window per batch mixes labels; jj<64 <=> jh==0
  const bool lastwin = ((w & 127) == 127);
  const float maskadd = (lastwin && ((i < 64) != (jh == 0))) ? -100.f : 0.f;
  const int bbase = i - jh * 64 + 127;

  float p[64];
  #pragma unroll
  for (int j = 0; j < 64; ++j) {
    const int jj = jh * 64 + j;
    float s = 0.f;
    #pragma unroll
    for (int d = 0; d < 32; d += 4) {
      float4 kv = *(const float4*)&ks[jj][d];
      s = fmaf(qr[d], kv.x, s);
      s = fmaf(qr[d + 1], kv.y, s);
      s = fmaf(qr[d + 2], kv.z, s);
      s = fmaf(qr[d + 3], kv.w, s);
    }
    p[j] = s * kinv[jj] + lbias[bbase - j] + maskadd;
  }

  float mx = -1e30f;
  #pragma unroll
  for (int j = 0; j < 64; ++j) mx = fmaxf(mx, p[j]);
  mx = fmaxf(mx, __shfl_xor(mx, 1));
  float sum = 0.f;
  #pragma unroll
  for (int j = 0; j < 64; ++j) { p[j] = __expf(p[j] - mx); sum += p[j]; }
  sum += __shfl_xor(sum, 1);
  const float sinv = 1.f / sum;

  float acc[32] = {};
  #pragma unroll
  for (int j = 0; j < 64; ++j) {
    const int jj = jh * 64 + j;
    const float pj = p[j] * sinv;
    #pragma unroll
    for (int d = 0; d < 32; d += 4) {
      float4 vv = *(const float4*)&vs[jj][d];
      acc[d]     = fmaf(pj, vv.x, acc[d]);
      acc[d + 1] = fmaf(pj, vv.y, acc[d + 1]);
      acc[d + 2] = fmaf(pj, vv.z, acc[d + 2]);
      acc[d + 3] = fmaf(pj, vv.w, acc[d + 3]);
    }
  }
  #pragma unroll
  for (int d = 0; d < 32; ++d) acc[d] += __shfl_xor(acc[d], 1);

  float ov[16];
  #pragma unroll
  for (int d = 0; d < 16; ++d) ov[d] = jh ? acc[16 + d] : acc[d];
  const long obase = (long)(w * 128 + i) * 512 + h * 32 + jh * 16;
  ushort8v s0, s1;
  #pragma unroll
  for (int e = 0; e < 8; ++e) { s0[e] = f2bf(ov[e]); s1[e] = f2bf(ov[8 + e]); }
  *(ushort8v*)(attnout + obase) = s0;
  *(ushort8v*)(attnout + obase + 8) = s1;
}

// CPB MLP: sig_tbl[i][n] = 16*sigmoid( relu(rel(i)*w1 + b1) @ w2[n] ), i in [0,255)
__global__ __launch_bounds__(256) void cpb_k(const float* __restrict__ w1,
    const float* __restrict__ b1, const float* __restrict__ w2,
    float* __restrict__ sig_tbl) {
  __shared__ float hbuf[512];
  const int i = blockIdx.x;
  const int tid = threadIdx.x;
  const float t = (float)(i - 127) * (8.f / 127.f);
  const float sgn = (t < 0.f) ? -1.f : 1.f;
  const float s = sgn * (log2f(fabsf(t) + 1.f) * (1.f / 3.f));
  hbuf[tid]       = fmaxf(s * w1[tid] + b1[tid], 0.f);
  hbuf[tid + 256] = fmaxf(s * w1[tid + 256] + b1[tid + 256], 0.f);
  __syncthreads();
  const int wv = tid >> 6, lane = tid & 63;
  for (int q = 0; q < 4; ++q) {
    const int n = wv * 4 + q;
    float part = 0.f;
    for (int c = lane; c < 512; c += 64) part += hbuf[c] * w2[n * 512 + c];
    #pragma unroll
    for (int o = 1; o < 64; o <<= 1) part += __shfl_xor(part, o);
    if (lane == 0) sig_tbl[i * 16 + n] = 16.f / (1.f + expf(-part));
  }
}

__global__ void qkvbias_k(const float* __restrict__ qb, const float* __restrict__ vb,
                          float* __restrict__ ob) {
  const int n = blockIdx.x * 256 + threadIdx.x;
  float v = 0.f;
  if (n < 512) v = qb[n];
  else if (n >= 1024) v = vb[n - 1024];
  ob[n] = v;
}

// x1[dest] = x[dest] + rmsnorm(proj[r]) ; dest = rolled-back row
__global__ __launch_bounds__(128) void addnorm_roll_k(const float* __restrict__ proj,
    const float* __restrict__ x, const float* __restrict__ nw, float* __restrict__ out) {
  const int r = blockIdx.x;
  const int tid = threadIdx.x;
  float4 v = *(const float4*)(proj + (long)r * 512 + tid * 4);
  float ss = v.x * v.x + v.y * v.y + v.z * v.z + v.w * v.w;
  #pragma unroll
  for (int o = 1; o < 64; o <<= 1) ss += __shfl_xor(ss, o);
  __shared__ float tot[2];
  if ((tid & 63) == 0) tot[tid >> 6] = ss;
  __syncthreads();
  const float inv = SQRT_C * rsqrtf((tot[0] + tot[1]) * (1.f / 512.f) + 1e-8f);
  const long b = r >> 14, l = r & LMASK;
  const long dest = (b << 14) + ((l + SS_SHIFT) & LMASK);
  float4 wv = *(const float4*)(nw + tid * 4);
  float4 xv = *(const float4*)(x + dest * 512 + tid * 4);
  float4 o4;
  o4.x = xv.x + v.x * inv * wv.x;
  o4.y = xv.y + v.y * inv * wv.y;
  o4.z = xv.z + v.z * inv * wv.z;
  o4.w = xv.w + v.w * inv * wv.w;
  *(float4*)(out + dest * 512 + tid * 4) = o4;
}

// out[r] += rmsnorm(y[r]) (y bf16), in place on d_out
__global__ __launch_bounds__(128) void addnorm_final_k(const unsigned short* __restrict__ y,
    const float* __restrict__ nw, float* __restrict__ out) {
  const int r = blockIdx.x;
  const int tid = threadIdx.x;
  ushort4v u = *(const ushort4v*)(y + (long)r * 512 + tid * 4);
  float v0 = bf2f(u[0]), v1 = bf2f(u[1]), v2 = bf2f(u[2]), v3 = bf2f(u[3]);
  float ss = v0 * v0 + v1 * v1 + v2 * v2 + v3 * v3;
  #pragma unroll
  for (int o = 1; o < 64; o <<= 1) ss += __shfl_xor(ss, o);
  __shared__ float tot[2];
  if ((tid & 63) == 0) tot[tid >> 6] = ss;
  __syncthreads();
  const float inv = SQRT_C * rsqrtf((tot[0] + tot[1]) * (1.f / 512.f) + 1e-8f);
  const long base = (long)r * 512 + tid * 4;
  float4 wv = *(const float4*)(nw + tid * 4);
  float4 xv = *(const float4*)(out + base);
  float4 o4;
  o4.x = xv.x + v0 * inv * wv.x;
  o4.y = xv.y + v1 * inv * wv.y;
  o4.z = xv.z + v2 * inv * wv.z;
  o4.w = xv.w + v3 * inv * wv.w;
  *(float4*)(out + base) = o4;
}

extern "C" void kernel_launch(void* const* d_in, const int* in_sizes, int n_in,
                              void* d_out, int out_size, void* d_ws, size_t ws_size,
                              hipStream_t stream) {
  const float* x       = (const float*)d_in[0];
  const float* qkv_w   = (const float*)d_in[1];
  const float* q_bias  = (const float*)d_in[2];
  const float* v_bias  = (const float*)d_in[3];
  const float* lscale  = (const float*)d_in[4];
  const float* cpb_w1  = (const float*)d_in[5];
  const float* cpb_b1  = (const float*)d_in[6];
  const float* cpb_w2  = (const float*)d_in[7];
  const float* proj_w  = (const float*)d_in[8];
  const float* proj_b  = (const float*)d_in[9];
  const float* norm1_w = (const float*)d_in[10];
  const float* norm2_w = (const float*)d_in[11];
  const float* mlp_w1  = (const float*)d_in[12];
  const float* mlp_b1  = (const float*)d_in[13];
  const float* mlp_w2  = (const float*)d_in[14];
  const float* mlp_b2  = (const float*)d_in[15];
  float* outp = (float*)d_out;
  char* ws = (char*)d_ws;

  // workspace layout (peak 160 MB + 24 KB), regions reused across phases:
  unsigned short* qkv     = (unsigned short*)(ws);               // [0,96M)  bf16 32768x1536
  unsigned short* attnout = (unsigned short*)(ws + 100663296);   // [96M,128M) bf16 32768x512
  float*          projout = (float*)(ws);                        // [0,64M)  f32 (reuse, qkv dead)
  unsigned short* h2      = (unsigned short*)(ws);               // [0,128M) bf16 32768x2048 (reuse)
  unsigned short* mlp2o   = (unsigned short*)(ws + 134217728);   // [128M,160M) bf16 32768x512
  float*          sig_tbl = (float*)(ws + 167772160);            // 255x16 f32
  float*          qkvb    = (float*)(ws + 167772160 + 16384);    // 1536 f32

  cpb_k<<<255, 256, 0, stream>>>(cpb_w1, cpb_b1, cpb_w2, sig_tbl);
  qkvbias_k<<<6, 256, 0, stream>>>(q_bias, v_bias, qkvb);
  // qkv = roll(x) @ qkv_w^T + qkv_bias   (M=32768, N=1536, K=512)
  gemm_k<0, 1, 0, 1><<<dim3(256, 12), 256, 0, stream>>>(x, qkv_w, qkvb, qkv, 32768, 1536, 512);
  attn_k<<<dim3(16, 256), 256, 0, stream>>>(qkv, lscale, sig_tbl, attnout);
  // projout = attnout @ proj_w^T + proj_b  (M=32768, N=512, K=512)
  gemm_k<1, 0, 0, 0><<<dim3(256, 4), 256, 0, stream>>>(attnout, proj_w, proj_b, projout, 32768, 512, 512);
  addnorm_roll_k<<<32768, 128, 0, stream>>>(projout, x, norm1_w, outp);
  // h2 = silu(x1 @ mlp_w1^T + b1)  (M=32768, N=2048, K=512)
  gemm_k<0, 1, 1, 0><<<dim3(256, 16), 256, 0, stream>>>(outp, mlp_w1, mlp_b1, h2, 32768, 2048, 512);
  // y = h2 @ mlp_w2^T + b2  (M=32768, N=512, K=2048)
  gemm_k<1, 1, 0, 0><<<dim3(256, 4), 256, 0, stream>>>(h2, mlp_w2, mlp_b2, mlp2o, 32768, 512, 2048);
  addnorm_final_k<<<32768, 128, 0, stream>>>(mlp2o, norm2_w, outp);
}

// Round 2
// 667.154 us; speedup vs baseline: 5.4694x; 5.4694x over previous
//
#include <hip/hip_runtime.h>

typedef __attribute__((ext_vector_type(8))) unsigned short us8;
typedef __attribute__((ext_vector_type(8))) short bf16x8;
typedef __attribute__((ext_vector_type(4))) float f32x4;

#define LMASK 16383
#define SQRT_C 22.627416997969522f
#define LOGIT_MAXV 4.605170185988091f

__device__ __forceinline__ float bf2f(unsigned short u) {
  unsigned int x = ((unsigned int)u) << 16;
  return __builtin_bit_cast(float, x);
}
__device__ __forceinline__ unsigned short f2bf(float f) {
  unsigned int x = __builtin_bit_cast(unsigned int, f);
  x = x + 0x7FFFu + ((x >> 16) & 1u);
  return (unsigned short)(x >> 16);
}
__device__ __forceinline__ void gload16(const void* g, void* lds) {
  __builtin_amdgcn_global_load_lds(
      (const __attribute__((address_space(1))) unsigned int*)g,
      (__attribute__((address_space(3))) unsigned int*)lds, 16, 0, 0);
}

// ---------------- generic f32 -> bf16 convert (8 elems/thread) ----------------
__global__ void cvt8_k(const float* __restrict__ src, unsigned short* __restrict__ dst, int n8) {
  int idx = blockIdx.x * 256 + threadIdx.x;
  if (idx >= n8) return;
  const float* s = src + (long)idx * 8;
  us8 u;
  #pragma unroll
  for (int e = 0; e < 8; ++e) u[e] = f2bf(s[e]);
  *(us8*)(dst + (long)idx * 8) = u;
}

// roll(x, -64) then convert to bf16
__global__ void rollcvt_k(const float* __restrict__ x, unsigned short* __restrict__ xb) {
  long e = ((long)blockIdx.x * 256 + threadIdx.x) * 8;
  long row = e >> 9;
  int col = (int)(e & 511);
  long src = ((row >> 14) << 14) | (((row & LMASK) + 64) & LMASK);
  const float* s = x + src * 512 + col;
  us8 u;
  #pragma unroll
  for (int ee = 0; ee < 8; ++ee) u[ee] = f2bf(s[ee]);
  *(us8*)(xb + e) = u;
}

// ---------------- CPB MLP table ----------------
__global__ __launch_bounds__(256) void cpb_k(const float* __restrict__ w1,
    const float* __restrict__ b1, const float* __restrict__ w2,
    float* __restrict__ sig_tbl) {
  __shared__ float hbuf[512];
  const int i = blockIdx.x;
  const int tid = threadIdx.x;
  const float t = (float)(i - 127) * (8.f / 127.f);
  const float sgn = (t < 0.f) ? -1.f : 1.f;
  const float s = sgn * (log2f(fabsf(t) + 1.f) * (1.f / 3.f));
  hbuf[tid]       = fmaxf(s * w1[tid] + b1[tid], 0.f);
  hbuf[tid + 256] = fmaxf(s * w1[tid + 256] + b1[tid + 256], 0.f);
  __syncthreads();
  const int wv = tid >> 6, lane = tid & 63;
  for (int q = 0; q < 4; ++q) {
    const int n = wv * 4 + q;
    float part = 0.f;
    for (int c = lane; c < 512; c += 64) part += hbuf[c] * w2[n * 512 + c];
    #pragma unroll
    for (int o = 1; o < 64; o <<= 1) part += __shfl_xor(part, o);
    if (lane == 0) sig_tbl[i * 16 + n] = 16.f / (1.f + expf(-part));
  }
}

__global__ void qkvbias_k(const float* __restrict__ qb, const float* __restrict__ vb,
                          float* __restrict__ ob) {
  const int n = blockIdx.x * 256 + threadIdx.x;
  float v = 0.f;
  if (n < 512) v = qb[n];
  else if (n >= 1024) v = vb[n - 1024];
  ob[n] = v;
}

// ---------------- MFMA GEMM, 128x128 tile, BK=32, 4 waves ----------------
// C[M,N] = A[M,K] @ B[N,K]^T + bias, output bf16. AREG: A is f32, reg-staged.
template<int AREG, int SILU>
__global__ __launch_bounds__(256) void gemm128_k(
    const void* __restrict__ Ap, const unsigned short* __restrict__ Bw,
    const float* __restrict__ bias, unsigned short* __restrict__ Cp,
    int N, int K) {
  __shared__ unsigned short As[128 * 32];
  __shared__ unsigned short Bs[128 * 32];
  const int tid = threadIdx.x;
  const int w = tid >> 6, l = tid & 63;
  const int wrow = w >> 1, wcol = w & 1;
  const int m0 = blockIdx.x * 128, n0 = blockIdx.y * 128;
  const int lr = l & 15, lh = l >> 4;
  f32x4 acc[4][4];
  #pragma unroll
  for (int m = 0; m < 4; ++m)
    #pragma unroll
    for (int n = 0; n < 4; ++n) acc[m][n] = (f32x4)0.f;
  int aoff[4], boff[4];
  #pragma unroll
  for (int m = 0; m < 4; ++m)
    aoff[m] = (wrow * 64 + m * 16 + lr) * 64 + ((lh ^ (lr & 3)) << 4);
  #pragma unroll
  for (int n = 0; n < 4; ++n)
    boff[n] = (wcol * 64 + n * 16 + lr) * 64 + ((lh ^ (lr & 3)) << 4);
  const int srow = l >> 2;
  const int schunk = (l & 3) ^ (srow & 3);
  const int rrow = tid >> 1, rhalf = tid & 1;  // reg-stage mapping

  for (int k0 = 0; k0 < K; k0 += 32) {
    __syncthreads();
    if constexpr (AREG == 0) {
      const unsigned short* A = (const unsigned short*)Ap;
      gload16(A + (long)(m0 + w * 16 + srow) * K + k0 + schunk * 8, (char*)As + w * 1024);
      gload16(A + (long)(m0 + 64 + w * 16 + srow) * K + k0 + schunk * 8, (char*)As + 4096 + w * 1024);
    } else {
      const float* A = (const float*)Ap;
      const float* sp = A + (long)(m0 + rrow) * K + k0 + rhalf * 16;
      us8 u0, u1;
      #pragma unroll
      for (int e = 0; e < 8; ++e) u0[e] = f2bf(sp[e]);
      #pragma unroll
      for (int e = 0; e < 8; ++e) u1[e] = f2bf(sp[8 + e]);
      *(us8*)((char*)As + rrow * 64 + (((rhalf * 2) ^ (rrow & 3)) << 4)) = u0;
      *(us8*)((char*)As + rrow * 64 + (((rhalf * 2 + 1) ^ (rrow & 3)) << 4)) = u1;
    }
    gload16(Bw + (long)(n0 + w * 16 + srow) * K + k0 + schunk * 8, (char*)Bs + w * 1024);
    gload16(Bw + (long)(n0 + 64 + w * 16 + srow) * K + k0 + schunk * 8, (char*)Bs + 4096 + w * 1024);
    __syncthreads();
    bf16x8 a[4], b[4];
    #pragma unroll
    for (int m = 0; m < 4; ++m) a[m] = *(const bf16x8*)((const char*)As + aoff[m]);
    #pragma unroll
    for (int n = 0; n < 4; ++n) b[n] = *(const bf16x8*)((const char*)Bs + boff[n]);
    #pragma unroll
    for (int m = 0; m < 4; ++m)
      #pragma unroll
      for (int n = 0; n < 4; ++n)
        acc[m][n] = __builtin_amdgcn_mfma_f32_16x16x32_bf16(a[m], b[n], acc[m][n], 0, 0, 0);
  }

  float bv[4];
  #pragma unroll
  for (int n = 0; n < 4; ++n) bv[n] = bias[n0 + wcol * 64 + n * 16 + lr];
  #pragma unroll
  for (int m = 0; m < 4; ++m)
    #pragma unroll
    for (int reg = 0; reg < 4; ++reg) {
      const long row = m0 + wrow * 64 + m * 16 + lh * 4 + reg;
      #pragma unroll
      for (int n = 0; n < 4; ++n) {
        const int col = n0 + wcol * 64 + n * 16 + lr;
        float v = acc[m][n][reg] + bv[n];
        if constexpr (SILU == 1) v = v / (1.f + __expf(-v));
        Cp[row * (long)N + col] = f2bf(v);
      }
    }
}

// ---------------- MFMA GEMM, 128x512 tile (full N), fused RMS-norm epilogue ----
// EPI 0: proj — out[dest] = resid[dest] + rms(val)*nw, dest = roll(row,+64)
// EPI 1: mlp2 — out[row]  = resid[row]  + rms(val)*nw
template<int EPI>
__global__ __launch_bounds__(512) void gemm512_k(
    const unsigned short* __restrict__ Ab, const unsigned short* __restrict__ Bw,
    const float* __restrict__ bias, const float* __restrict__ resid,
    const float* __restrict__ nw, float* __restrict__ outp, int K) {
  __shared__ unsigned short As[128 * 32];
  __shared__ unsigned short Bs[512 * 32];
  __shared__ float rsum[128][4];
  __shared__ float rinv[128];
  const int tid = threadIdx.x;
  const int ww = tid >> 6, l = tid & 63;
  const int wrow = ww >> 2, wcol = ww & 3;
  const int m0 = blockIdx.x * 128;
  const int lr = l & 15, lh = l >> 4;
  f32x4 acc[4][8];
  #pragma unroll
  for (int m = 0; m < 4; ++m)
    #pragma unroll
    for (int n = 0; n < 8; ++n) acc[m][n] = (f32x4)0.f;
  int aoff[4], boff[8];
  #pragma unroll
  for (int m = 0; m < 4; ++m)
    aoff[m] = (wrow * 64 + m * 16 + lr) * 64 + ((lh ^ (lr & 3)) << 4);
  #pragma unroll
  for (int n = 0; n < 8; ++n)
    boff[n] = (wcol * 128 + n * 16 + lr) * 64 + ((lh ^ (lr & 3)) << 4);
  const int srow = l >> 2;
  const int schunk = (l & 3) ^ (srow & 3);

  for (int k0 = 0; k0 < K; k0 += 32) {
    __syncthreads();
    gload16(Ab + (long)(m0 + ww * 16 + srow) * K + k0 + schunk * 8, (char*)As + ww * 1024);
    #pragma unroll
    for (int c = 0; c < 4; ++c)
      gload16(Bw + (long)(c * 128 + ww * 16 + srow) * K + k0 + schunk * 8,
              (char*)Bs + c * 8192 + ww * 1024);
    __syncthreads();
    bf16x8 a[4], b[8];
    #pragma unroll
    for (int m = 0; m < 4; ++m) a[m] = *(const bf16x8*)((const char*)As + aoff[m]);
    #pragma unroll
    for (int n = 0; n < 8; ++n) b[n] = *(const bf16x8*)((const char*)Bs + boff[n]);
    #pragma unroll
    for (int m = 0; m < 4; ++m)
      #pragma unroll
      for (int n = 0; n < 8; ++n)
        acc[m][n] = __builtin_amdgcn_mfma_f32_16x16x32_bf16(a[m], b[n], acc[m][n], 0, 0, 0);
  }

  float bv[8], nwv[8];
  #pragma unroll
  for (int n = 0; n < 8; ++n) {
    const int col = wcol * 128 + n * 16 + lr;
    bv[n] = bias[col];
    nwv[n] = nw[col];
  }
  float part[4][4];
  #pragma unroll
  for (int m = 0; m < 4; ++m)
    #pragma unroll
    for (int reg = 0; reg < 4; ++reg) {
      float s = 0.f;
      #pragma unroll
      for (int n = 0; n < 8; ++n) {
        float v = acc[m][n][reg] + bv[n];
        s += v * v;
      }
      part[m][reg] = s;
    }
  #pragma unroll
  for (int off = 1; off < 16; off <<= 1)
    #pragma unroll
    for (int m = 0; m < 4; ++m)
      #pragma unroll
      for (int reg = 0; reg < 4; ++reg)
        part[m][reg] += __shfl_xor(part[m][reg], off);
  if (lr == 0) {
    #pragma unroll
    for (int m = 0; m < 4; ++m)
      #pragma unroll
      for (int reg = 0; reg < 4; ++reg)
        rsum[wrow * 64 + m * 16 + lh * 4 + reg][wcol] = part[m][reg];
  }
  __syncthreads();
  if (tid < 128) {
    float s = rsum[tid][0] + rsum[tid][1] + rsum[tid][2] + rsum[tid][3];
    rinv[tid] = SQRT_C * rsqrtf(s * (1.f / 512.f) + 1e-8f);
  }
  __syncthreads();
  #pragma unroll
  for (int m = 0; m < 4; ++m)
    #pragma unroll
    for (int reg = 0; reg < 4; ++reg) {
      const int rl = wrow * 64 + m * 16 + lh * 4 + reg;
      const long grow = m0 + rl;
      const float inv = rinv[rl];
      long orow;
      if constexpr (EPI == 0)
        orow = (grow & ~(long)LMASK) | (((grow & LMASK) + 64) & LMASK);
      else
        orow = grow;
      #pragma unroll
      for (int n = 0; n < 8; ++n) {
        const int col = wcol * 128 + n * 16 + lr;
        float v = acc[m][n][reg] + bv[n];
        outp[orow * 512 + col] = resid[orow * 512 + col] + v * inv * nwv[n];
      }
    }
}

// ---------------- attention: 4 lanes per query row, 64 rows/block ----------------
__global__ __launch_bounds__(256, 3) void attn_k(const unsigned short* __restrict__ qkv,
    const float* __restrict__ logit_scale, const float* __restrict__ sig_tbl,
    unsigned short* __restrict__ attnout) {
  __shared__ float qs[64][36];
  __shared__ float ks[128][36];
  __shared__ float vs[128][36];
  __shared__ float qinv[64], kinv[128], lbias[255];
  const int h = blockIdx.x, w = blockIdx.y, bz = blockIdx.z;
  const int tid = threadIdx.x;

  {  // stage q: 64 rows x 32
    const int r = tid >> 2, c = tid & 3;
    const long ga = (long)(w * 128 + bz * 64 + r) * 1536 + h * 32 + c * 8;
    us8 u = *(const us8*)(qkv + ga);
    #pragma unroll
    for (int e = 0; e < 8; ++e) qs[r][c * 8 + e] = bf2f(u[e]);
  }
  #pragma unroll
  for (int it = 0; it < 2; ++it) {  // stage k, v: 128 rows x 32 each
    const int idx = tid + it * 256;
    const int r = idx >> 2, c = idx & 3;
    const long ga = (long)(w * 128 + r) * 1536 + h * 32 + c * 8;
    us8 uk = *(const us8*)(qkv + ga + 512);
    us8 uv = *(const us8*)(qkv + ga + 1024);
    #pragma unroll
    for (int e = 0; e < 8; ++e) {
      ks[r][c * 8 + e] = bf2f(uk[e]);
      vs[r][c * 8 + e] = bf2f(uv[e]);
    }
  }
  if (tid < 255) lbias[tid] = sig_tbl[tid * 16 + h];
  __syncthreads();

  const float scale = __expf(fminf(logit_scale[h], LOGIT_MAXV));
  if (tid < 192) {
    const int r = (tid < 64) ? tid : (tid - 64);
    float s = 0.f;
    if (tid < 64) {
      #pragma unroll
      for (int d = 0; d < 32; d += 4) {
        float4 v = *(const float4*)&qs[r][d];
        s += v.x * v.x + v.y * v.y + v.z * v.z + v.w * v.w;
      }
      qinv[r] = scale / fmaxf(sqrtf(s), 1e-12f);
    } else {
      #pragma unroll
      for (int d = 0; d < 32; d += 4) {
        float4 v = *(const float4*)&ks[r][d];
        s += v.x * v.x + v.y * v.y + v.z * v.z + v.w * v.w;
      }
      kinv[r] = 1.f / fmaxf(sqrtf(s), 1e-12f);
    }
  }
  __syncthreads();

  const int i = tid >> 2, jq = tid & 3;
  const int iw = bz * 64 + i;
  float qr[32];
  {
    const float qi = qinv[i];
    #pragma unroll
    for (int d = 0; d < 32; d += 4) {
      float4 v = *(const float4*)&qs[i][d];
      qr[d] = v.x * qi; qr[d + 1] = v.y * qi; qr[d + 2] = v.z * qi; qr[d + 3] = v.w * qi;
    }
  }
  const bool lastwin = ((w & 127) == 127);
  float p[32];
  #pragma unroll
  for (int j = 0; j < 32; ++j) {
    const int jj = j * 4 + jq;
    float s = 0.f;
    #pragma unroll
    for (int d = 0; d < 32; d += 4) {
      float4 kv = *(const float4*)&ks[jj][d];
      s = fmaf(qr[d], kv.x, s);
      s = fmaf(qr[d + 1], kv.y, s);
      s = fmaf(qr[d + 2], kv.z, s);
      s = fmaf(qr[d + 3], kv.w, s);
    }
    const float maskadd = (lastwin && ((iw < 64) != (jj < 64))) ? -100.f : 0.f;
    p[j] = s * kinv[jj] + lbias[iw - jj + 127] + maskadd;
  }

  float mx = -1e30f;
  #pragma unroll
  for (int j = 0; j < 32; ++j) mx = fmaxf(mx, p[j]);
  mx = fmaxf(mx, __shfl_xor(mx, 1));
  mx = fmaxf(mx, __shfl_xor(mx, 2));
  float sum = 0.f;
  #pragma unroll
  for (int j = 0; j < 32; ++j) { p[j] = __expf(p[j] - mx); sum += p[j]; }
  sum += __shfl_xor(sum, 1);
  sum += __shfl_xor(sum, 2);
  const float sinv = 1.f / sum;

  float acc[32];
  #pragma unroll
  for (int d = 0; d < 32; ++d) acc[d] = 0.f;
  #pragma unroll
  for (int j = 0; j < 32; ++j) {
    const int jj = j * 4 + jq;
    const float pj = p[j] * sinv;
    #pragma unroll
    for (int d = 0; d < 32; d += 4) {
      float4 vv = *(const float4*)&vs[jj][d];
      acc[d]     = fmaf(pj, vv.x, acc[d]);
      acc[d + 1] = fmaf(pj, vv.y, acc[d + 1]);
      acc[d + 2] = fmaf(pj, vv.z, acc[d + 2]);
      acc[d + 3] = fmaf(pj, vv.w, acc[d + 3]);
    }
  }
  #pragma unroll
  for (int d = 0; d < 32; ++d) {
    acc[d] += __shfl_xor(acc[d], 1);
    acc[d] += __shfl_xor(acc[d], 2);
  }
  us8 o;
  #pragma unroll
  for (int e = 0; e < 8; ++e) o[e] = f2bf(acc[jq * 8 + e]);
  *(us8*)(attnout + (long)(w * 128 + iw) * 512 + h * 32 + jq * 8) = o;
}

// ---------------- launch ----------------
extern "C" void kernel_launch(void* const* d_in, const int* in_sizes, int n_in,
                              void* d_out, int out_size, void* d_ws, size_t ws_size,
                              hipStream_t stream) {
  const float* x       = (const float*)d_in[0];
  const float* qkv_w   = (const float*)d_in[1];
  const float* q_bias  = (const float*)d_in[2];
  const float* v_bias  = (const float*)d_in[3];
  const float* lscale  = (const float*)d_in[4];
  const float* cpb_w1  = (const float*)d_in[5];
  const float* cpb_b1  = (const float*)d_in[6];
  const float* cpb_w2  = (const float*)d_in[7];
  const float* proj_w  = (const float*)d_in[8];
  const float* proj_b  = (const float*)d_in[9];
  const float* norm1_w = (const float*)d_in[10];
  const float* norm2_w = (const float*)d_in[11];
  const float* mlp_w1  = (const float*)d_in[12];
  const float* mlp_b1  = (const float*)d_in[13];
  const float* mlp_w2  = (const float*)d_in[14];
  const float* mlp_b2  = (const float*)d_in[15];
  float* outp = (float*)d_out;
  char* ws = (char*)d_ws;

  // workspace (peak 136 MB):
  unsigned short* w1b     = (unsigned short*)(ws + 0);          // 2 MB
  unsigned short* w2b     = (unsigned short*)(ws + 2097152);    // 2 MB
  unsigned short* qkv_wb  = (unsigned short*)(ws + 4194304);    // 1.5 MB
  unsigned short* proj_wb = (unsigned short*)(ws + 5767168);    // 0.5 MB
  float*          sig_tbl = (float*)(ws + 6291456);             // 16 KB
  float*          qkvb    = (float*)(ws + 6311936);             // 6 KB
  unsigned short* xb      = (unsigned short*)(ws + 8388608);    // 32 MB (dead after qkv gemm)
  unsigned short* attnout = (unsigned short*)(ws + 8388608);    // 32 MB (reuse xb)
  unsigned short* h2      = (unsigned short*)(ws + 8388608);    // 128 MB (reuse, all prior dead)
  unsigned short* qkvbuf  = (unsigned short*)(ws + 41943040);   // 96 MB

  cvt8_k<<<512, 256, 0, stream>>>(mlp_w1, w1b, 131072);
  cvt8_k<<<512, 256, 0, stream>>>(mlp_w2, w2b, 131072);
  cvt8_k<<<384, 256, 0, stream>>>(qkv_w, qkv_wb, 98304);
  cvt8_k<<<128, 256, 0, stream>>>(proj_w, proj_wb, 32768);
  rollcvt_k<<<8192, 256, 0, stream>>>(x, xb);
  cpb_k<<<255, 256, 0, stream>>>(cpb_w1, cpb_b1, cpb_w2, sig_tbl);
  qkvbias_k<<<6, 256, 0, stream>>>(q_bias, v_bias, qkvb);

  // qkv = xb @ qkv_w^T + qkvb   (M=32768, N=1536, K=512)
  gemm128_k<0, 0><<<dim3(256, 12), 256, 0, stream>>>(xb, qkv_wb, qkvb, qkvbuf, 1536, 512);
  // attention
  attn_k<<<dim3(16, 256, 2), 256, 0, stream>>>(qkvbuf, lscale, sig_tbl, attnout);
  // proj + rms-norm1 + rolled residual -> outp
  gemm512_k<0><<<256, 512, 0, stream>>>(attnout, proj_wb, proj_b, x, norm1_w, outp, 512);
  // h2 = silu(outp @ w1^T + b1)  (M=32768, N=2048, K=512), A reg-staged f32
  gemm128_k<1, 1><<<dim3(256, 16), 256, 0, stream>>>(outp, w1b, mlp_b1, h2, 2048, 512);
  // mlp2 + rms-norm2 + residual (in place on outp)
  gemm512_k<1><<<256, 512, 0, stream>>>(h2, w2b, mlp_b2, outp, norm2_w, outp, 2048);
}

// Round 3
// 528.379 us; speedup vs baseline: 6.9059x; 1.2626x over previous
//
#include <hip/hip_runtime.h>

typedef __attribute__((ext_vector_type(8))) unsigned short us8;
typedef __attribute__((ext_vector_type(8))) short bf16x8;
typedef __attribute__((ext_vector_type(4))) float f32x4;

#define LMASK 16383
#define SQRT_C 22.627416997969522f
#define LOGIT_MAXV 4.605170185988091f

__device__ __forceinline__ float bf2f(unsigned short u) {
  unsigned int x = ((unsigned int)u) << 16;
  return __builtin_bit_cast(float, x);
}
__device__ __forceinline__ unsigned short f2bf(float f) {
  unsigned int x = __builtin_bit_cast(unsigned int, f);
  x = x + 0x7FFFu + ((x >> 16) & 1u);
  return (unsigned short)(x >> 16);
}
__device__ __forceinline__ void gload16(const void* g, void* lds) {
  __builtin_amdgcn_global_load_lds(
      (const __attribute__((address_space(1))) unsigned int*)g,
      (__attribute__((address_space(3))) unsigned int*)lds, 16, 0, 0);
}

// ---------------- generic f32 -> bf16 convert (8 elems/thread) ----------------
__global__ void cvt8_k(const float* __restrict__ src, unsigned short* __restrict__ dst, int n8) {
  int idx = blockIdx.x * 256 + threadIdx.x;
  if (idx >= n8) return;
  const float* s = src + (long)idx * 8;
  us8 u;
  #pragma unroll
  for (int e = 0; e < 8; ++e) u[e] = f2bf(s[e]);
  *(us8*)(dst + (long)idx * 8) = u;
}

// roll(x, -64) then convert to bf16
__global__ void rollcvt_k(const float* __restrict__ x, unsigned short* __restrict__ xb) {
  long e = ((long)blockIdx.x * 256 + threadIdx.x) * 8;
  long row = e >> 9;
  int col = (int)(e & 511);
  long src = ((row >> 14) << 14) | (((row & LMASK) + 64) & LMASK);
  const float* s = x + src * 512 + col;
  us8 u;
  #pragma unroll
  for (int ee = 0; ee < 8; ++ee) u[ee] = f2bf(s[ee]);
  *(us8*)(xb + e) = u;
}

// ---------------- CPB MLP table ----------------
__global__ __launch_bounds__(256) void cpb_k(const float* __restrict__ w1,
    const float* __restrict__ b1, const float* __restrict__ w2,
    float* __restrict__ sig_tbl) {
  __shared__ float hbuf[512];
  const int i = blockIdx.x;
  const int tid = threadIdx.x;
  const float t = (float)(i - 127) * (8.f / 127.f);
  const float sgn = (t < 0.f) ? -1.f : 1.f;
  const float s = sgn * (log2f(fabsf(t) + 1.f) * (1.f / 3.f));
  hbuf[tid]       = fmaxf(s * w1[tid] + b1[tid], 0.f);
  hbuf[tid + 256] = fmaxf(s * w1[tid + 256] + b1[tid + 256], 0.f);
  __syncthreads();
  const int wv = tid >> 6, lane = tid & 63;
  for (int q = 0; q < 4; ++q) {
    const int n = wv * 4 + q;
    float part = 0.f;
    for (int c = lane; c < 512; c += 64) part += hbuf[c] * w2[n * 512 + c];
    #pragma unroll
    for (int o = 1; o < 64; o <<= 1) part += __shfl_xor(part, o);
    if (lane == 0) sig_tbl[i * 16 + n] = 16.f / (1.f + expf(-part));
  }
}

__global__ void qkvbias_k(const float* __restrict__ qb, const float* __restrict__ vb,
                          float* __restrict__ ob) {
  const int n = blockIdx.x * 256 + threadIdx.x;
  float v = 0.f;
  if (n < 512) v = qb[n];
  else if (n >= 1024) v = vb[n - 1024];
  ob[n] = v;
}

// ---------------- MFMA GEMM, 128x128 tile, BK=32, 4 waves ----------------
template<int AREG, int SILU>
__global__ __launch_bounds__(256) void gemm128_k(
    const void* __restrict__ Ap, const unsigned short* __restrict__ Bw,
    const float* __restrict__ bias, unsigned short* __restrict__ Cp,
    int N, int K) {
  __shared__ unsigned short As[128 * 32];
  __shared__ unsigned short Bs[128 * 32];
  const int tid = threadIdx.x;
  const int w = tid >> 6, l = tid & 63;
  const int wrow = w >> 1, wcol = w & 1;
  const int m0 = blockIdx.x * 128, n0 = blockIdx.y * 128;
  const int lr = l & 15, lh = l >> 4;
  f32x4 acc[4][4];
  #pragma unroll
  for (int m = 0; m < 4; ++m)
    #pragma unroll
    for (int n = 0; n < 4; ++n) acc[m][n] = (f32x4)0.f;
  const int fsw = (lr >> 1) & 3;
  int aoff[4], boff[4];
  #pragma unroll
  for (int m = 0; m < 4; ++m)
    aoff[m] = (wrow * 64 + m * 16 + lr) * 64 + ((lh ^ fsw) << 4);
  #pragma unroll
  for (int n = 0; n < 4; ++n)
    boff[n] = (wcol * 64 + n * 16 + lr) * 64 + ((lh ^ fsw) << 4);
  const int srow = l >> 2;
  const int schunk = (l & 3) ^ ((srow >> 1) & 3);
  const int rrow = tid >> 1, rhalf = tid & 1;
  const int rsw = (rrow >> 1) & 3;

  for (int k0 = 0; k0 < K; k0 += 32) {
    __syncthreads();
    if constexpr (AREG == 0) {
      const unsigned short* A = (const unsigned short*)Ap;
      gload16(A + (long)(m0 + w * 16 + srow) * K + k0 + schunk * 8, (char*)As + w * 1024);
      gload16(A + (long)(m0 + 64 + w * 16 + srow) * K + k0 + schunk * 8, (char*)As + 4096 + w * 1024);
    } else {
      const float* A = (const float*)Ap;
      const float* sp = A + (long)(m0 + rrow) * K + k0 + rhalf * 16;
      us8 u0, u1;
      #pragma unroll
      for (int e = 0; e < 8; ++e) u0[e] = f2bf(sp[e]);
      #pragma unroll
      for (int e = 0; e < 8; ++e) u1[e] = f2bf(sp[8 + e]);
      *(us8*)((char*)As + rrow * 64 + (((rhalf * 2) ^ rsw) << 4)) = u0;
      *(us8*)((char*)As + rrow * 64 + (((rhalf * 2 + 1) ^ rsw) << 4)) = u1;
    }
    gload16(Bw + (long)(n0 + w * 16 + srow) * K + k0 + schunk * 8, (char*)Bs + w * 1024);
    gload16(Bw + (long)(n0 + 64 + w * 16 + srow) * K + k0 + schunk * 8, (char*)Bs + 4096 + w * 1024);
    __syncthreads();
    bf16x8 a[4], b[4];
    #pragma unroll
    for (int m = 0; m < 4; ++m) a[m] = *(const bf16x8*)((const char*)As + aoff[m]);
    #pragma unroll
    for (int n = 0; n < 4; ++n) b[n] = *(const bf16x8*)((const char*)Bs + boff[n]);
    #pragma unroll
    for (int m = 0; m < 4; ++m)
      #pragma unroll
      for (int n = 0; n < 4; ++n)
        acc[m][n] = __builtin_amdgcn_mfma_f32_16x16x32_bf16(a[m], b[n], acc[m][n], 0, 0, 0);
  }

  float bv[4];
  #pragma unroll
  for (int n = 0; n < 4; ++n) bv[n] = bias[n0 + wcol * 64 + n * 16 + lr];
  #pragma unroll
  for (int m = 0; m < 4; ++m)
    #pragma unroll
    for (int reg = 0; reg < 4; ++reg) {
      const long row = m0 + wrow * 64 + m * 16 + lh * 4 + reg;
      #pragma unroll
      for (int n = 0; n < 4; ++n) {
        const int col = n0 + wcol * 64 + n * 16 + lr;
        float v = acc[m][n][reg] + bv[n];
        if constexpr (SILU == 1) v = v / (1.f + __expf(-v));
        Cp[row * (long)N + col] = f2bf(v);
      }
    }
}

// ---------------- MFMA GEMM, 128x512 tile, fused RMS-norm epilogue ----
// EPI 0: proj — out[dest] = resid[dest] + rms(val)*nw, dest = roll(row,+64)
// EPI 1: mlp2 — out[row]  = resid[row]  + rms(val)*nw
template<int EPI>
__global__ __launch_bounds__(512) void gemm512_k(
    const unsigned short* __restrict__ Ab, const unsigned short* __restrict__ Bw,
    const float* __restrict__ bias, const float* __restrict__ resid,
    const float* __restrict__ nw, float* __restrict__ outp, int K) {
  __shared__ unsigned short As[128 * 32];
  __shared__ unsigned short Bs[512 * 32];
  __shared__ float rsum[128][4];
  __shared__ float rinv[128];
  const int tid = threadIdx.x;
  const int ww = tid >> 6, l = tid & 63;
  const int wrow = ww >> 2, wcol = ww & 3;
  const int m0 = blockIdx.x * 128;
  const int lr = l & 15, lh = l >> 4;
  f32x4 acc[4][8];
  #pragma unroll
  for (int m = 0; m < 4; ++m)
    #pragma unroll
    for (int n = 0; n < 8; ++n) acc[m][n] = (f32x4)0.f;
  const int fsw = (lr >> 1) & 3;
  int aoff[4], boff[8];
  #pragma unroll
  for (int m = 0; m < 4; ++m)
    aoff[m] = (wrow * 64 + m * 16 + lr) * 64 + ((lh ^ fsw) << 4);
  #pragma unroll
  for (int n = 0; n < 8; ++n)
    boff[n] = (wcol * 128 + n * 16 + lr) * 64 + ((lh ^ fsw) << 4);
  const int srow = l >> 2;
  const int schunk = (l & 3) ^ ((srow >> 1) & 3);

  for (int k0 = 0; k0 < K; k0 += 32) {
    __syncthreads();
    gload16(Ab + (long)(m0 + ww * 16 + srow) * K + k0 + schunk * 8, (char*)As + ww * 1024);
    #pragma unroll
    for (int c = 0; c < 4; ++c)
      gload16(Bw + (long)(c * 128 + ww * 16 + srow) * K + k0 + schunk * 8,
              (char*)Bs + c * 8192 + ww * 1024);
    __syncthreads();
    bf16x8 a[4], b[8];
    #pragma unroll
    for (int m = 0; m < 4; ++m) a[m] = *(const bf16x8*)((const char*)As + aoff[m]);
    #pragma unroll
    for (int n = 0; n < 8; ++n) b[n] = *(const bf16x8*)((const char*)Bs + boff[n]);
    #pragma unroll
    for (int m = 0; m < 4; ++m)
      #pragma unroll
      for (int n = 0; n < 8; ++n)
        acc[m][n] = __builtin_amdgcn_mfma_f32_16x16x32_bf16(a[m], b[n], acc[m][n], 0, 0, 0);
  }

  float bv[8], nwv[8];
  #pragma unroll
  for (int n = 0; n < 8; ++n) {
    const int col = wcol * 128 + n * 16 + lr;
    bv[n] = bias[col];
    nwv[n] = nw[col];
  }
  float part[4][4];
  #pragma unroll
  for (int m = 0; m < 4; ++m)
    #pragma unroll
    for (int reg = 0; reg < 4; ++reg) {
      float s = 0.f;
      #pragma unroll
      for (int n = 0; n < 8; ++n) {
        float v = acc[m][n][reg] + bv[n];
        s += v * v;
      }
      part[m][reg] = s;
    }
  #pragma unroll
  for (int off = 1; off < 16; off <<= 1)
    #pragma unroll
    for (int m = 0; m < 4; ++m)
      #pragma unroll
      for (int reg = 0; reg < 4; ++reg)
        part[m][reg] += __shfl_xor(part[m][reg], off);
  if (lr == 0) {
    #pragma unroll
    for (int m = 0; m < 4; ++m)
      #pragma unroll
      for (int reg = 0; reg < 4; ++reg)
        rsum[wrow * 64 + m * 16 + lh * 4 + reg][wcol] = part[m][reg];
  }
  __syncthreads();
  if (tid < 128) {
    float s = rsum[tid][0] + rsum[tid][1] + rsum[tid][2] + rsum[tid][3];
    rinv[tid] = SQRT_C * rsqrtf(s * (1.f / 512.f) + 1e-8f);
  }
  __syncthreads();
  #pragma unroll
  for (int m = 0; m < 4; ++m)
    #pragma unroll
    for (int reg = 0; reg < 4; ++reg) {
      const int rl = wrow * 64 + m * 16 + lh * 4 + reg;
      const long grow = m0 + rl;
      const float inv = rinv[rl];
      long orow;
      if constexpr (EPI == 0)
        orow = (grow & ~(long)LMASK) | (((grow & LMASK) + 64) & LMASK);
      else
        orow = grow;
      #pragma unroll
      for (int n = 0; n < 8; ++n) {
        const int col = wcol * 128 + n * 16 + lr;
        float v = acc[m][n][reg] + bv[n];
        outp[orow * 512 + col] = resid[orow * 512 + col] + v * inv * nwv[n];
      }
    }
}

// ---------------- attention via MFMA: one block per (head, window) ----------------
__global__ __launch_bounds__(256, 2) void attn_k(const unsigned short* __restrict__ qkv,
    const float* __restrict__ logit_scale, const float* __restrict__ sig_tbl,
    unsigned short* __restrict__ attnout) {
  __shared__ unsigned short qs[128 * 32];   // swizzled rows of 64B
  __shared__ unsigned short ks[128 * 32];
  __shared__ unsigned short vt[32 * 136];   // V^T: vt[d][j], row stride 136
  __shared__ unsigned short ps[128 * 136];  // P~ bf16, row stride 136
  __shared__ float qinv[128], kinv[128], lbias[256];
  const int h = blockIdx.x, w = blockIdx.y;
  const int tid = threadIdx.x;
  const int wv = tid >> 6, l = tid & 63;
  const int lr = l & 15, quad = l >> 4;

  // ---- stage q, k (swizzled, via global_load_lds with pre-swizzled source) ----
  {
    const int srow = l >> 2;
    const int cs = (l & 3) ^ ((srow >> 1) & 3);
    #pragma unroll
    for (int rnd = 0; rnd < 2; ++rnd) {
      const int row = wv * 32 + rnd * 16 + srow;
      const long gb = (long)(w * 128 + row) * 1536 + h * 32 + cs * 8;
      gload16(qkv + gb, (char*)qs + (wv * 32 + rnd * 16) * 64);
      gload16(qkv + gb + 512, (char*)ks + (wv * 32 + rnd * 16) * 64);
    }
  }
  // ---- stage V transposed ----
  #pragma unroll
  for (int rnd = 0; rnd < 2; ++rnd) {
    const int j = wv * 32 + rnd * 16 + (l >> 2);
    const int d0 = (l & 3) * 8;
    us8 uv = *(const us8*)(qkv + (long)(w * 128 + j) * 1536 + h * 32 + 1024 + d0);
    #pragma unroll
    for (int e = 0; e < 8; ++e) vt[(d0 + e) * 136 + j] = uv[e];
  }
  if (tid < 255) lbias[tid] = sig_tbl[tid * 16 + h];
  __syncthreads();

  // ---- row norms: 2 threads per row ----
  const float scale = __expf(fminf(logit_scale[h], LOGIT_MAXV));
  {
    const int r = tid >> 1, cp = tid & 1;
    const int sw = (r >> 1) & 3;
    float sq = 0.f, sk = 0.f;
    #pragma unroll
    for (int cc = 0; cc < 2; ++cc) {
      const int slot = (cp * 2 + cc) ^ sw;
      us8 uq = *(const us8*)(qs + r * 32 + slot * 8);
      us8 uk = *(const us8*)(ks + r * 32 + slot * 8);
      #pragma unroll
      for (int e = 0; e < 8; ++e) {
        float fq = bf2f(uq[e]), fk = bf2f(uk[e]);
        sq = fmaf(fq, fq, sq);
        sk = fmaf(fk, fk, sk);
      }
    }
    sq += __shfl_xor(sq, 1);
    sk += __shfl_xor(sk, 1);
    qinv[r] = scale / fmaxf(sqrtf(sq), 1e-12f);
    kinv[r] = 1.f / fmaxf(sqrtf(sk), 1e-12f);
  }
  __syncthreads();

  // ---- S = Q K^T (wave wv owns rows [wv*32, wv*32+32)) ----
  const int fsw = (lr >> 1) & 3;
  bf16x8 aq[2];
  #pragma unroll
  for (int mt = 0; mt < 2; ++mt)
    aq[mt] = *(const bf16x8*)((const char*)qs + (wv * 32 + mt * 16 + lr) * 64 + ((quad ^ fsw) << 4));
  f32x4 s[2][8];
  #pragma unroll
  for (int nt = 0; nt < 8; ++nt) {
    bf16x8 bk = *(const bf16x8*)((const char*)ks + (nt * 16 + lr) * 64 + ((quad ^ fsw) << 4));
    #pragma unroll
    for (int mt = 0; mt < 2; ++mt)
      s[mt][nt] = __builtin_amdgcn_mfma_f32_16x16x32_bf16(aq[mt], bk, (f32x4)0.f, 0, 0, 0);
  }

  // ---- scale + bias + mask + softmax (unnormalized), store P~ to LDS ----
  float kv8[8];
  #pragma unroll
  for (int nt = 0; nt < 8; ++nt) kv8[nt] = kinv[nt * 16 + lr];
  const bool lastwin = ((w & 127) == 127);
  const bool ihalf = (wv < 2);
  float sum[2][4];
  #pragma unroll
  for (int mt = 0; mt < 2; ++mt) {
    #pragma unroll
    for (int reg = 0; reg < 4; ++reg) {
      const int row = wv * 32 + mt * 16 + quad * 4 + reg;
      const float qv = qinv[row];
      const int bb = row + 127 - lr;
      float m = -1e30f;
      #pragma unroll
      for (int nt = 0; nt < 8; ++nt) {
        float v = s[mt][nt][reg] * qv * kv8[nt] + lbias[bb - nt * 16];
        if (lastwin && (ihalf != (nt < 4))) v -= 100.f;
        s[mt][nt][reg] = v;
        m = fmaxf(m, v);
      }
      m = fmaxf(m, __shfl_xor(m, 1));
      m = fmaxf(m, __shfl_xor(m, 2));
      m = fmaxf(m, __shfl_xor(m, 4));
      m = fmaxf(m, __shfl_xor(m, 8));
      float sm = 0.f;
      #pragma unroll
      for (int nt = 0; nt < 8; ++nt) {
        float p = __expf(s[mt][nt][reg] - m);
        s[mt][nt][reg] = p;
        sm += p;
      }
      sm += __shfl_xor(sm, 1);
      sm += __shfl_xor(sm, 2);
      sm += __shfl_xor(sm, 4);
      sm += __shfl_xor(sm, 8);
      sum[mt][reg] = sm;
      #pragma unroll
      for (int nt = 0; nt < 8; ++nt)
        ps[row * 136 + nt * 16 + lr] = f2bf(s[mt][nt][reg]);
    }
  }
  __syncthreads();

  // ---- O = P~ V via MFMA, then scale rows by 1/sum ----
  f32x4 o[2][2];
  #pragma unroll
  for (int mt = 0; mt < 2; ++mt)
    #pragma unroll
    for (int nt = 0; nt < 2; ++nt) o[mt][nt] = (f32x4)0.f;
  #pragma unroll
  for (int kt = 0; kt < 4; ++kt) {
    bf16x8 pa[2], vb[2];
    #pragma unroll
    for (int mt = 0; mt < 2; ++mt)
      pa[mt] = *(const bf16x8*)((const char*)ps + (wv * 32 + mt * 16 + lr) * 272 + (kt * 4 + quad) * 16);
    #pragma unroll
    for (int nt = 0; nt < 2; ++nt)
      vb[nt] = *(const bf16x8*)((const char*)vt + (nt * 16 + lr) * 272 + (kt * 4 + quad) * 16);
    #pragma unroll
    for (int mt = 0; mt < 2; ++mt)
      #pragma unroll
      for (int nt = 0; nt < 2; ++nt)
        o[mt][nt] = __builtin_amdgcn_mfma_f32_16x16x32_bf16(pa[mt], vb[nt], o[mt][nt], 0, 0, 0);
  }
  #pragma unroll
  for (int mt = 0; mt < 2; ++mt) {
    #pragma unroll
    for (int reg = 0; reg < 4; ++reg) {
      const int row = wv * 32 + mt * 16 + quad * 4 + reg;
      const float si = 1.f / sum[mt][reg];
      const long ob = (long)(w * 128 + row) * 512 + h * 32;
      attnout[ob + lr]      = f2bf(o[mt][0][reg] * si);
      attnout[ob + 16 + lr] = f2bf(o[mt][1][reg] * si);
    }
  }
}

// ---------------- launch ----------------
extern "C" void kernel_launch(void* const* d_in, const int* in_sizes, int n_in,
                              void* d_out, int out_size, void* d_ws, size_t ws_size,
                              hipStream_t stream) {
  const float* x       = (const float*)d_in[0];
  const float* qkv_w   = (const float*)d_in[1];
  const float* q_bias  = (const float*)d_in[2];
  const float* v_bias  = (const float*)d_in[3];
  const float* lscale  = (const float*)d_in[4];
  const float* cpb_w1  = (const float*)d_in[5];
  const float* cpb_b1  = (const float*)d_in[6];
  const float* cpb_w2  = (const float*)d_in[7];
  const float* proj_w  = (const float*)d_in[8];
  const float* proj_b  = (const float*)d_in[9];
  const float* norm1_w = (const float*)d_in[10];
  const float* norm2_w = (const float*)d_in[11];
  const float* mlp_w1  = (const float*)d_in[12];
  const float* mlp_b1  = (const float*)d_in[13];
  const float* mlp_w2  = (const float*)d_in[14];
  const float* mlp_b2  = (const float*)d_in[15];
  float* outp = (float*)d_out;
  char* ws = (char*)d_ws;

  unsigned short* w1b     = (unsigned short*)(ws + 0);          // 2 MB
  unsigned short* w2b     = (unsigned short*)(ws + 2097152);    // 2 MB
  unsigned short* qkv_wb  = (unsigned short*)(ws + 4194304);    // 1.5 MB
  unsigned short* proj_wb = (unsigned short*)(ws + 5767168);    // 0.5 MB
  float*          sig_tbl = (float*)(ws + 6291456);             // 16 KB
  float*          qkvb    = (float*)(ws + 6311936);             // 6 KB
  unsigned short* xb      = (unsigned short*)(ws + 8388608);    // 32 MB
  unsigned short* attnout = (unsigned short*)(ws + 8388608);    // 32 MB (reuse xb)
  unsigned short* h2      = (unsigned short*)(ws + 8388608);    // 128 MB (reuse)
  unsigned short* qkvbuf  = (unsigned short*)(ws + 41943040);   // 96 MB

  cvt8_k<<<512, 256, 0, stream>>>(mlp_w1, w1b, 131072);
  cvt8_k<<<512, 256, 0, stream>>>(mlp_w2, w2b, 131072);
  cvt8_k<<<384, 256, 0, stream>>>(qkv_w, qkv_wb, 98304);
  cvt8_k<<<128, 256, 0, stream>>>(proj_w, proj_wb, 32768);
  rollcvt_k<<<8192, 256, 0, stream>>>(x, xb);
  cpb_k<<<255, 256, 0, stream>>>(cpb_w1, cpb_b1, cpb_w2, sig_tbl);
  qkvbias_k<<<6, 256, 0, stream>>>(q_bias, v_bias, qkvb);

  // qkv = xb @ qkv_w^T + qkvb
  gemm128_k<0, 0><<<dim3(256, 12), 256, 0, stream>>>(xb, qkv_wb, qkvb, qkvbuf, 1536, 512);
  // attention (MFMA)
  attn_k<<<dim3(16, 256), 256, 0, stream>>>(qkvbuf, lscale, sig_tbl, attnout);
  // proj + rms-norm1 + rolled residual -> outp
  gemm512_k<0><<<256, 512, 0, stream>>>(attnout, proj_wb, proj_b, x, norm1_w, outp, 512);
  // h2 = silu(outp @ w1^T + b1), A reg-staged f32
  gemm128_k<1, 1><<<dim3(256, 16), 256, 0, stream>>>(outp, w1b, mlp_b1, h2, 2048, 512);
  // mlp2 + rms-norm2 + residual (in place on outp)
  gemm512_k<1><<<256, 512, 0, stream>>>(h2, w2b, mlp_b2, outp, norm2_w, outp, 2048);
}

// Round 4
// 499.068 us; speedup vs baseline: 7.3115x; 1.0587x over previous
//
#include <hip/hip_runtime.h>

typedef __attribute__((ext_vector_type(8))) unsigned short us8;
typedef __attribute__((ext_vector_type(8))) short bf16x8;
typedef __attribute__((ext_vector_type(4))) float f32x4;

#define LMASK 16383
#define SQRT_C 22.627416997969522f
#define LOGIT_MAXV 4.605170185988091f

__device__ __forceinline__ float bf2f(unsigned short u) {
  unsigned int x = ((unsigned int)u) << 16;
  return __builtin_bit_cast(float, x);
}
__device__ __forceinline__ unsigned short f2bf(float f) {
  unsigned int x = __builtin_bit_cast(unsigned int, f);
  x = x + 0x7FFFu + ((x >> 16) & 1u);
  return (unsigned short)(x >> 16);
}
__device__ __forceinline__ void gload16(const void* g, void* lds) {
  __builtin_amdgcn_global_load_lds(
      (const __attribute__((address_space(1))) unsigned int*)g,
      (__attribute__((address_space(3))) unsigned int*)lds, 16, 0, 0);
}

// ---------------- generic f32 -> bf16 convert (8 elems/thread) ----------------
__global__ void cvt8_k(const float* __restrict__ src, unsigned short* __restrict__ dst, int n8) {
  int idx = blockIdx.x * 256 + threadIdx.x;
  if (idx >= n8) return;
  const float* s = src + (long)idx * 8;
  us8 u;
  #pragma unroll
  for (int e = 0; e < 8; ++e) u[e] = f2bf(s[e]);
  *(us8*)(dst + (long)idx * 8) = u;
}

// roll(x, -64) then convert to bf16
__global__ void rollcvt_k(const float* __restrict__ x, unsigned short* __restrict__ xb) {
  long e = ((long)blockIdx.x * 256 + threadIdx.x) * 8;
  long row = e >> 9;
  int col = (int)(e & 511);
  long src = ((row >> 14) << 14) | (((row & LMASK) + 64) & LMASK);
  const float* s = x + src * 512 + col;
  us8 u;
  #pragma unroll
  for (int ee = 0; ee < 8; ++ee) u[ee] = f2bf(s[ee]);
  *(us8*)(xb + e) = u;
}

// ---------------- CPB MLP table ----------------
__global__ __launch_bounds__(256) void cpb_k(const float* __restrict__ w1,
    const float* __restrict__ b1, const float* __restrict__ w2,
    float* __restrict__ sig_tbl) {
  __shared__ float hbuf[512];
  const int i = blockIdx.x;
  const int tid = threadIdx.x;
  const float t = (float)(i - 127) * (8.f / 127.f);
  const float sgn = (t < 0.f) ? -1.f : 1.f;
  const float s = sgn * (log2f(fabsf(t) + 1.f) * (1.f / 3.f));
  hbuf[tid]       = fmaxf(s * w1[tid] + b1[tid], 0.f);
  hbuf[tid + 256] = fmaxf(s * w1[tid + 256] + b1[tid + 256], 0.f);
  __syncthreads();
  const int wv = tid >> 6, lane = tid & 63;
  for (int q = 0; q < 4; ++q) {
    const int n = wv * 4 + q;
    float part = 0.f;
    for (int c = lane; c < 512; c += 64) part += hbuf[c] * w2[n * 512 + c];
    #pragma unroll
    for (int o = 1; o < 64; o <<= 1) part += __shfl_xor(part, o);
    if (lane == 0) sig_tbl[i * 16 + n] = 16.f / (1.f + expf(-part));
  }
}

__global__ void qkvbias_k(const float* __restrict__ qb, const float* __restrict__ vb,
                          float* __restrict__ ob) {
  const int n = blockIdx.x * 256 + threadIdx.x;
  float v = 0.f;
  if (n < 512) v = qb[n];
  else if (n >= 1024) v = vb[n - 1024];
  ob[n] = v;
}

// ---------------- MFMA GEMM, 128x128 tile, BK=32, 2-phase double-buffered ----
// 1-D grid, XCD-chunked (m,n) mapping, n-fast within chunk for A L2 reuse.
template<int NY, int AREG, int SILU>
__global__ __launch_bounds__(256) void gemm128_k(
    const void* __restrict__ Ap, const unsigned short* __restrict__ Bw,
    const float* __restrict__ bias, unsigned short* __restrict__ Cp, int K) {
  __shared__ unsigned short As[2][128 * 32];
  __shared__ unsigned short Bs[2][128 * 32];
  const int N = NY * 128;
  const int tid = threadIdx.x;
  const int w = tid >> 6, l = tid & 63;
  const int wrow = w >> 1, wcol = w & 1;
  const int nwg = gridDim.x;
  const int id = blockIdx.x;
  const int lid = (id & 7) * (nwg >> 3) + (id >> 3);
  const int mi = lid / NY, ni = lid % NY;
  const int m0 = mi * 128, n0 = ni * 128;
  const int lr = l & 15, lh = l >> 4;
  f32x4 acc[4][4];
  #pragma unroll
  for (int m = 0; m < 4; ++m)
    #pragma unroll
    for (int n = 0; n < 4; ++n) acc[m][n] = (f32x4)0.f;
  const int fsw = (lr >> 1) & 3;
  int aoff[4], boff[4];
  #pragma unroll
  for (int m = 0; m < 4; ++m)
    aoff[m] = (wrow * 64 + m * 16 + lr) * 64 + ((lh ^ fsw) << 4);
  #pragma unroll
  for (int n = 0; n < 4; ++n)
    boff[n] = (wcol * 64 + n * 16 + lr) * 64 + ((lh ^ fsw) << 4);
  const int srow = l >> 2;
  const int schunk = (l & 3) ^ ((srow >> 1) & 3);
  const int rrow = tid >> 1, rhalf = tid & 1;
  const int rsw = (rrow >> 1) & 3;
  const int rslot0 = ((rhalf * 2) ^ rsw) << 4;
  const int rslot1 = ((rhalf * 2 + 1) ^ rsw) << 4;
  const unsigned short* A = (const unsigned short*)Ap;
  const float* Af = (const float*)Ap;
  const int NT = K >> 5;

  // ---- prologue: stage tile 0 into buffer 0 ----
  if constexpr (AREG == 0) {
    gload16(A + (long)(m0 + w * 16 + srow) * K + schunk * 8, (char*)As[0] + w * 1024);
    gload16(A + (long)(m0 + 64 + w * 16 + srow) * K + schunk * 8, (char*)As[0] + 4096 + w * 1024);
  } else {
    const float* sp = Af + (long)(m0 + rrow) * K + rhalf * 16;
    us8 u0, u1;
    #pragma unroll
    for (int e = 0; e < 8; ++e) u0[e] = f2bf(sp[e]);
    #pragma unroll
    for (int e = 0; e < 8; ++e) u1[e] = f2bf(sp[8 + e]);
    *(us8*)((char*)As[0] + rrow * 64 + rslot0) = u0;
    *(us8*)((char*)As[0] + rrow * 64 + rslot1) = u1;
  }
  gload16(Bw + (long)(n0 + w * 16 + srow) * K + schunk * 8, (char*)Bs[0] + w * 1024);
  gload16(Bw + (long)(n0 + 64 + w * 16 + srow) * K + schunk * 8, (char*)Bs[0] + 4096 + w * 1024);
  __syncthreads();

  int cur = 0;
  for (int t = 0; t < NT; ++t) {
    const int kn = (t + 1) << 5;
    // issue next-tile staging (writes buf cur^1; overlaps this tile's MFMA)
    float4 ga0, ga1, ga2, ga3;
    if (t + 1 < NT) {
      if constexpr (AREG == 0) {
        gload16(A + (long)(m0 + w * 16 + srow) * K + kn + schunk * 8,
                (char*)As[cur ^ 1] + w * 1024);
        gload16(A + (long)(m0 + 64 + w * 16 + srow) * K + kn + schunk * 8,
                (char*)As[cur ^ 1] + 4096 + w * 1024);
      } else {
        const float* sp = Af + (long)(m0 + rrow) * K + kn + rhalf * 16;
        ga0 = *(const float4*)(sp);
        ga1 = *(const float4*)(sp + 4);
        ga2 = *(const float4*)(sp + 8);
        ga3 = *(const float4*)(sp + 12);
      }
      gload16(Bw + (long)(n0 + w * 16 + srow) * K + kn + schunk * 8,
              (char*)Bs[cur ^ 1] + w * 1024);
      gload16(Bw + (long)(n0 + 64 + w * 16 + srow) * K + kn + schunk * 8,
              (char*)Bs[cur ^ 1] + 4096 + w * 1024);
    }
    // fragments from current buffer
    bf16x8 a[4], b[4];
    #pragma unroll
    for (int m = 0; m < 4; ++m) a[m] = *(const bf16x8*)((const char*)As[cur] + aoff[m]);
    #pragma unroll
    for (int n = 0; n < 4; ++n) b[n] = *(const bf16x8*)((const char*)Bs[cur] + boff[n]);
    #pragma unroll
    for (int m = 0; m < 4; ++m)
      #pragma unroll
      for (int n = 0; n < 4; ++n)
        acc[m][n] = __builtin_amdgcn_mfma_f32_16x16x32_bf16(a[m], b[n], acc[m][n], 0, 0, 0);
    // AREG: convert + LDS-write AFTER the MFMA so the vmcnt wait hides under it
    if constexpr (AREG == 1) {
      if (t + 1 < NT) {
        us8 u0, u1;
        u0[0] = f2bf(ga0.x); u0[1] = f2bf(ga0.y); u0[2] = f2bf(ga0.z); u0[3] = f2bf(ga0.w);
        u0[4] = f2bf(ga1.x); u0[5] = f2bf(ga1.y); u0[6] = f2bf(ga1.z); u0[7] = f2bf(ga1.w);
        u1[0] = f2bf(ga2.x); u1[1] = f2bf(ga2.y); u1[2] = f2bf(ga2.z); u1[3] = f2bf(ga2.w);
        u1[4] = f2bf(ga3.x); u1[5] = f2bf(ga3.y); u1[6] = f2bf(ga3.z); u1[7] = f2bf(ga3.w);
        *(us8*)((char*)As[cur ^ 1] + rrow * 64 + rslot0) = u0;
        *(us8*)((char*)As[cur ^ 1] + rrow * 64 + rslot1) = u1;
      }
    }
    __syncthreads();
    cur ^= 1;
  }

  float bv[4];
  #pragma unroll
  for (int n = 0; n < 4; ++n) bv[n] = bias[n0 + wcol * 64 + n * 16 + lr];
  #pragma unroll
  for (int m = 0; m < 4; ++m)
    #pragma unroll
    for (int reg = 0; reg < 4; ++reg) {
      const long row = m0 + wrow * 64 + m * 16 + lh * 4 + reg;
      #pragma unroll
      for (int n = 0; n < 4; ++n) {
        const int col = n0 + wcol * 64 + n * 16 + lr;
        float v = acc[m][n][reg] + bv[n];
        if constexpr (SILU == 1) v = v / (1.f + __expf(-v));
        Cp[row * (long)N + col] = f2bf(v);
      }
    }
}

// ---------------- MFMA GEMM, 128x512 tile, fused RMS-norm epilogue ----
// EPI 0: proj — out[dest] = resid[dest] + rms(val)*nw, dest = roll(row,+64)
// EPI 1: mlp2 — out[row]  = resid[row]  + rms(val)*nw
template<int EPI>
__global__ __launch_bounds__(512) void gemm512_k(
    const unsigned short* __restrict__ Ab, const unsigned short* __restrict__ Bw,
    const float* __restrict__ bias, const float* __restrict__ resid,
    const float* __restrict__ nw, float* __restrict__ outp, int K) {
  __shared__ unsigned short As[128 * 32];
  __shared__ unsigned short Bs[512 * 32];
  __shared__ float rsum[128][4];
  __shared__ float rinv[128];
  const int tid = threadIdx.x;
  const int ww = tid >> 6, l = tid & 63;
  const int wrow = ww >> 2, wcol = ww & 3;
  const int m0 = blockIdx.x * 128;
  const int lr = l & 15, lh = l >> 4;
  f32x4 acc[4][8];
  #pragma unroll
  for (int m = 0; m < 4; ++m)
    #pragma unroll
    for (int n = 0; n < 8; ++n) acc[m][n] = (f32x4)0.f;
  const int fsw = (lr >> 1) & 3;
  int aoff[4], boff[8];
  #pragma unroll
  for (int m = 0; m < 4; ++m)
    aoff[m] = (wrow * 64 + m * 16 + lr) * 64 + ((lh ^ fsw) << 4);
  #pragma unroll
  for (int n = 0; n < 8; ++n)
    boff[n] = (wcol * 128 + n * 16 + lr) * 64 + ((lh ^ fsw) << 4);
  const int srow = l >> 2;
  const int schunk = (l & 3) ^ ((srow >> 1) & 3);

  for (int k0 = 0; k0 < K; k0 += 32) {
    __syncthreads();
    gload16(Ab + (long)(m0 + ww * 16 + srow) * K + k0 + schunk * 8, (char*)As + ww * 1024);
    #pragma unroll
    for (int c = 0; c < 4; ++c)
      gload16(Bw + (long)(c * 128 + ww * 16 + srow) * K + k0 + schunk * 8,
              (char*)Bs + c * 8192 + ww * 1024);
    __syncthreads();
    bf16x8 a[4], b[8];
    #pragma unroll
    for (int m = 0; m < 4; ++m) a[m] = *(const bf16x8*)((const char*)As + aoff[m]);
    #pragma unroll
    for (int n = 0; n < 8; ++n) b[n] = *(const bf16x8*)((const char*)Bs + boff[n]);
    #pragma unroll
    for (int m = 0; m < 4; ++m)
      #pragma unroll
      for (int n = 0; n < 8; ++n)
        acc[m][n] = __builtin_amdgcn_mfma_f32_16x16x32_bf16(a[m], b[n], acc[m][n], 0, 0, 0);
  }

  float bv[8], nwv[8];
  #pragma unroll
  for (int n = 0; n < 8; ++n) {
    const int col = wcol * 128 + n * 16 + lr;
    bv[n] = bias[col];
    nwv[n] = nw[col];
  }
  float part[4][4];
  #pragma unroll
  for (int m = 0; m < 4; ++m)
    #pragma unroll
    for (int reg = 0; reg < 4; ++reg) {
      float s = 0.f;
      #pragma unroll
      for (int n = 0; n < 8; ++n) {
        float v = acc[m][n][reg] + bv[n];
        s += v * v;
      }
      part[m][reg] = s;
    }
  #pragma unroll
  for (int off = 1; off < 16; off <<= 1)
    #pragma unroll
    for (int m = 0; m < 4; ++m)
      #pragma unroll
      for (int reg = 0; reg < 4; ++reg)
        part[m][reg] += __shfl_xor(part[m][reg], off);
  if (lr == 0) {
    #pragma unroll
    for (int m = 0; m < 4; ++m)
      #pragma unroll
      for (int reg = 0; reg < 4; ++reg)
        rsum[wrow * 64 + m * 16 + lh * 4 + reg][wcol] = part[m][reg];
  }
  __syncthreads();
  if (tid < 128) {
    float s = rsum[tid][0] + rsum[tid][1] + rsum[tid][2] + rsum[tid][3];
    rinv[tid] = SQRT_C * rsqrtf(s * (1.f / 512.f) + 1e-8f);
  }
  __syncthreads();
  #pragma unroll
  for (int m = 0; m < 4; ++m)
    #pragma unroll
    for (int reg = 0; reg < 4; ++reg) {
      const int rl = wrow * 64 + m * 16 + lh * 4 + reg;
      const long grow = m0 + rl;
      const float inv = rinv[rl];
      long orow;
      if constexpr (EPI == 0)
        orow = (grow & ~(long)LMASK) | (((grow & LMASK) + 64) & LMASK);
      else
        orow = grow;
      #pragma unroll
      for (int n = 0; n < 8; ++n) {
        const int col = wcol * 128 + n * 16 + lr;
        float v = acc[m][n][reg] + bv[n];
        outp[orow * 512 + col] = resid[orow * 512 + col] + v * inv * nwv[n];
      }
    }
}

// ---------------- attention via MFMA: one block per (head, window) ----------------
__global__ __launch_bounds__(256, 2) void attn_k(const unsigned short* __restrict__ qkv,
    const float* __restrict__ logit_scale, const float* __restrict__ sig_tbl,
    unsigned short* __restrict__ attnout) {
  __shared__ unsigned short qs[128 * 32];   // swizzled rows of 64B
  __shared__ unsigned short ks[128 * 32];
  __shared__ unsigned short vt[32 * 136];   // V^T: vt[d][j], row stride 136
  __shared__ unsigned short ps[128 * 136];  // P~ bf16, row stride 136
  __shared__ float qinv[128], kinv[128], lbias[256];
  const int h = blockIdx.x, w = blockIdx.y;
  const int tid = threadIdx.x;
  const int wv = tid >> 6, l = tid & 63;
  const int lr = l & 15, quad = l >> 4;

  {
    const int srow = l >> 2;
    const int cs = (l & 3) ^ ((srow >> 1) & 3);
    #pragma unroll
    for (int rnd = 0; rnd < 2; ++rnd) {
      const int row = wv * 32 + rnd * 16 + srow;
      const long gb = (long)(w * 128 + row) * 1536 + h * 32 + cs * 8;
      gload16(qkv + gb, (char*)qs + (wv * 32 + rnd * 16) * 64);
      gload16(qkv + gb + 512, (char*)ks + (wv * 32 + rnd * 16) * 64);
    }
  }
  #pragma unroll
  for (int rnd = 0; rnd < 2; ++rnd) {
    const int j = wv * 32 + rnd * 16 + (l >> 2);
    const int d0 = (l & 3) * 8;
    us8 uv = *(const us8*)(qkv + (long)(w * 128 + j) * 1536 + h * 32 + 1024 + d0);
    #pragma unroll
    for (int e = 0; e < 8; ++e) vt[(d0 + e) * 136 + j] = uv[e];
  }
  if (tid < 255) lbias[tid] = sig_tbl[tid * 16 + h];
  __syncthreads();

  const float scale = __expf(fminf(logit_scale[h], LOGIT_MAXV));
  {
    const int r = tid >> 1, cp = tid & 1;
    const int sw = (r >> 1) & 3;
    float sq = 0.f, sk = 0.f;
    #pragma unroll
    for (int cc = 0; cc < 2; ++cc) {
      const int slot = (cp * 2 + cc) ^ sw;
      us8 uq = *(const us8*)(qs + r * 32 + slot * 8);
      us8 uk = *(const us8*)(ks + r * 32 + slot * 8);
      #pragma unroll
      for (int e = 0; e < 8; ++e) {
        float fq = bf2f(uq[e]), fk = bf2f(uk[e]);
        sq = fmaf(fq, fq, sq);
        sk = fmaf(fk, fk, sk);
      }
    }
    sq += __shfl_xor(sq, 1);
    sk += __shfl_xor(sk, 1);
    qinv[r] = scale / fmaxf(sqrtf(sq), 1e-12f);
    kinv[r] = 1.f / fmaxf(sqrtf(sk), 1e-12f);
  }
  __syncthreads();

  const int fsw = (lr >> 1) & 3;
  bf16x8 aq[2];
  #pragma unroll
  for (int mt = 0; mt < 2; ++mt)
    aq[mt] = *(const bf16x8*)((const char*)qs + (wv * 32 + mt * 16 + lr) * 64 + ((quad ^ fsw) << 4));
  f32x4 s[2][8];
  #pragma unroll
  for (int nt = 0; nt < 8; ++nt) {
    bf16x8 bk = *(const bf16x8*)((const char*)ks + (nt * 16 + lr) * 64 + ((quad ^ fsw) << 4));
    #pragma unroll
    for (int mt = 0; mt < 2; ++mt)
      s[mt][nt] = __builtin_amdgcn_mfma_f32_16x16x32_bf16(aq[mt], bk, (f32x4)0.f, 0, 0, 0);
  }

  float kv8[8];
  #pragma unroll
  for (int nt = 0; nt < 8; ++nt) kv8[nt] = kinv[nt * 16 + lr];
  const bool lastwin = ((w & 127) == 127);
  const bool ihalf = (wv < 2);
  float sum[2][4];
  #pragma unroll
  for (int mt = 0; mt < 2; ++mt) {
    #pragma unroll
    for (int reg = 0; reg < 4; ++reg) {
      const int row = wv * 32 + mt * 16 + quad * 4 + reg;
      const float qv = qinv[row];
      const int bb = row + 127 - lr;
      float m = -1e30f;
      #pragma unroll
      for (int nt = 0; nt < 8; ++nt) {
        float v = s[mt][nt][reg] * qv * kv8[nt] + lbias[bb - nt * 16];
        if (lastwin && (ihalf != (nt < 4))) v -= 100.f;
        s[mt][nt][reg] = v;
        m = fmaxf(m, v);
      }
      m = fmaxf(m, __shfl_xor(m, 1));
      m = fmaxf(m, __shfl_xor(m, 2));
      m = fmaxf(m, __shfl_xor(m, 4));
      m = fmaxf(m, __shfl_xor(m, 8));
      float sm = 0.f;
      #pragma unroll
      for (int nt = 0; nt < 8; ++nt) {
        float p = __expf(s[mt][nt][reg] - m);
        s[mt][nt][reg] = p;
        sm += p;
      }
      sm += __shfl_xor(sm, 1);
      sm += __shfl_xor(sm, 2);
      sm += __shfl_xor(sm, 4);
      sm += __shfl_xor(sm, 8);
      sum[mt][reg] = sm;
      #pragma unroll
      for (int nt = 0; nt < 8; ++nt)
        ps[row * 136 + nt * 16 + lr] = f2bf(s[mt][nt][reg]);
    }
  }
  __syncthreads();

  f32x4 o[2][2];
  #pragma unroll
  for (int mt = 0; mt < 2; ++mt)
    #pragma unroll
    for (int nt = 0; nt < 2; ++nt) o[mt][nt] = (f32x4)0.f;
  #pragma unroll
  for (int kt = 0; kt < 4; ++kt) {
    bf16x8 pa[2], vb[2];
    #pragma unroll
    for (int mt = 0; mt < 2; ++mt)
      pa[mt] = *(const bf16x8*)((const char*)ps + (wv * 32 + mt * 16 + lr) * 272 + (kt * 4 + quad) * 16);
    #pragma unroll
    for (int nt = 0; nt < 2; ++nt)
      vb[nt] = *(const bf16x8*)((const char*)vt + (nt * 16 + lr) * 272 + (kt * 4 + quad) * 16);
    #pragma unroll
    for (int mt = 0; mt < 2; ++mt)
      #pragma unroll
      for (int nt = 0; nt < 2; ++nt)
        o[mt][nt] = __builtin_amdgcn_mfma_f32_16x16x32_bf16(pa[mt], vb[nt], o[mt][nt], 0, 0, 0);
  }
  #pragma unroll
  for (int mt = 0; mt < 2; ++mt) {
    #pragma unroll
    for (int reg = 0; reg < 4; ++reg) {
      const int row = wv * 32 + mt * 16 + quad * 4 + reg;
      const float si = 1.f / sum[mt][reg];
      const long ob = (long)(w * 128 + row) * 512 + h * 32;
      attnout[ob + lr]      = f2bf(o[mt][0][reg] * si);
      attnout[ob + 16 + lr] = f2bf(o[mt][1][reg] * si);
    }
  }
}

// ---------------- launch ----------------
extern "C" void kernel_launch(void* const* d_in, const int* in_sizes, int n_in,
                              void* d_out, int out_size, void* d_ws, size_t ws_size,
                              hipStream_t stream) {
  const float* x       = (const float*)d_in[0];
  const float* qkv_w   = (const float*)d_in[1];
  const float* q_bias  = (const float*)d_in[2];
  const float* v_bias  = (const float*)d_in[3];
  const float* lscale  = (const float*)d_in[4];
  const float* cpb_w1  = (const float*)d_in[5];
  const float* cpb_b1  = (const float*)d_in[6];
  const float* cpb_w2  = (const float*)d_in[7];
  const float* proj_w  = (const float*)d_in[8];
  const float* proj_b  = (const float*)d_in[9];
  const float* norm1_w = (const float*)d_in[10];
  const float* norm2_w = (const float*)d_in[11];
  const float* mlp_w1  = (const float*)d_in[12];
  const float* mlp_b1  = (const float*)d_in[13];
  const float* mlp_w2  = (const float*)d_in[14];
  const float* mlp_b2  = (const float*)d_in[15];
  float* outp = (float*)d_out;
  char* ws = (char*)d_ws;

  unsigned short* w1b     = (unsigned short*)(ws + 0);          // 2 MB
  unsigned short* w2b     = (unsigned short*)(ws + 2097152);    // 2 MB
  unsigned short* qkv_wb  = (unsigned short*)(ws + 4194304);    // 1.5 MB
  unsigned short* proj_wb = (unsigned short*)(ws + 5767168);    // 0.5 MB
  float*          sig_tbl = (float*)(ws + 6291456);             // 16 KB
  float*          qkvb    = (float*)(ws + 6311936);             // 6 KB
  unsigned short* xb      = (unsigned short*)(ws + 8388608);    // 32 MB
  unsigned short* attnout = (unsigned short*)(ws + 8388608);    // 32 MB (reuse xb)
  unsigned short* h2      = (unsigned short*)(ws + 8388608);    // 128 MB (reuse)
  unsigned short* qkvbuf  = (unsigned short*)(ws + 41943040);   // 96 MB

  cvt8_k<<<512, 256, 0, stream>>>(mlp_w1, w1b, 131072);
  cvt8_k<<<512, 256, 0, stream>>>(mlp_w2, w2b, 131072);
  cvt8_k<<<384, 256, 0, stream>>>(qkv_w, qkv_wb, 98304);
  cvt8_k<<<128, 256, 0, stream>>>(proj_w, proj_wb, 32768);
  rollcvt_k<<<8192, 256, 0, stream>>>(x, xb);
  cpb_k<<<255, 256, 0, stream>>>(cpb_w1, cpb_b1, cpb_w2, sig_tbl);
  qkvbias_k<<<6, 256, 0, stream>>>(q_bias, v_bias, qkvb);

  // qkv = xb @ qkv_w^T + qkvb   (M=32768, N=1536, K=512)
  gemm128_k<12, 0, 0><<<3072, 256, 0, stream>>>(xb, qkv_wb, qkvb, qkvbuf, 512);
  // attention (MFMA)
  attn_k<<<dim3(16, 256), 256, 0, stream>>>(qkvbuf, lscale, sig_tbl, attnout);
  // proj + rms-norm1 + rolled residual -> outp
  gemm512_k<0><<<256, 512, 0, stream>>>(attnout, proj_wb, proj_b, x, norm1_w, outp, 512);
  // h2 = silu(outp @ w1^T + b1)  (M=32768, N=2048, K=512), A reg-staged f32
  gemm128_k<16, 1, 1><<<4096, 256, 0, stream>>>(outp, w1b, mlp_b1, h2, 512);
  // mlp2 + rms-norm2 + residual (in place on outp)
  gemm512_k<1><<<256, 512, 0, stream>>>(h2, w2b, mlp_b2, outp, norm2_w, outp, 2048);
}